// Round 8
// baseline (145.801 us; speedup 1.0000x reference)
//
#include <hip/hip_runtime.h>

namespace {

constexpr int OUT_F = 11008;
constexpr int IN_F  = 4096;
constexpr int R4    = IN_F / 4;          // 1024 vec4 per row (x and qw)
constexpr int NLOAD = IN_F / (64 * 4);   // 16 int4 loads per lane per row
constexpr int NBLK  = 512;               // persistent: 2 blocks/CU
constexpr int NWAVE = NBLK * 4;          // 2048 waves

typedef int   int4v   __attribute__((ext_vector_type(4)));
typedef float float4v __attribute__((ext_vector_type(4)));

__global__ __launch_bounds__(256, 2) void qlinear_kernel(
    const float* __restrict__ x,       // [4, IN_F]
    const int*   __restrict__ qw,      // [OUT_F, IN_F]
    const float* __restrict__ scales,  // [OUT_F]
    const float* __restrict__ bias,    // [OUT_F]
    float*       __restrict__ out)     // [4, OUT_F]
{
    __shared__ float4v xs[4 * R4];     // 64 KB fp32 (exact), staged ONCE

    const int tid  = threadIdx.x;
    const int lane = tid & 63;
    const int wid  = tid >> 6;
    const int wave_gid = blockIdx.x * 4 + wid;   // 0..2047, < OUT_F

    const int4v* qw4 = (const int4v*)qw;

    // Single per-row weight buffer: 64 VGPRs, statically indexed everywhere.
    int4v buf[NLOAD];

    // Issue first row's weights BEFORE staging x: HBM pipe busy during stage.
    {
        const int4v* wp = qw4 + (size_t)wave_gid * R4;
#pragma unroll
        for (int i = 0; i < NLOAD; ++i)
            buf[i] = wp[i * 64 + lane];
    }

    const float4v* xg = (const float4v*)x;
#pragma unroll
    for (int j = 0; j < (4 * R4) / 256; ++j)     // 16 iters x 256 threads
        xs[j * 256 + tid] = xg[j * 256 + tid];
    __syncthreads();

    int row = wave_gid;
    while (row < OUT_F) {
        const int nrow = row + NWAVE;

        // Dot products for this row against all 4 batch rows.
        float acc[4] = {0.f, 0.f, 0.f, 0.f};
#pragma unroll
        for (int k = 0; k < NLOAD; ++k) {
            float4v xv[4];
#pragma unroll
            for (int b = 0; b < 4; ++b)
                xv[b] = xs[b * R4 + k * 64 + lane];
            float4v wf;
            wf.x = (float)buf[k].x;
            wf.y = (float)buf[k].y;
            wf.z = (float)buf[k].z;
            wf.w = (float)buf[k].w;
#pragma unroll
            for (int b = 0; b < 4; ++b) {
                acc[b] += wf.x * xv[b].x;
                acc[b] += wf.y * xv[b].y;
                acc[b] += wf.z * xv[b].z;
                acc[b] += wf.w * xv[b].w;
            }
        }

        // Issue next row's loads now — they fly during the butterfly+store.
        // (WAR on buf is safe: in-order issue means each buf[k]'s last VALU
        // read precedes the new load's writeback.)
        if (nrow < OUT_F) {
            const int4v* wp = qw4 + (size_t)nrow * R4;
#pragma unroll
            for (int i = 0; i < NLOAD; ++i)
                buf[i] = wp[i * 64 + lane];
        }

        // Butterfly reduction across the 64 lanes.
#pragma unroll
        for (int b = 0; b < 4; ++b) {
#pragma unroll
            for (int m = 32; m >= 1; m >>= 1)
                acc[b] += __shfl_xor(acc[b], m, 64);
        }

        if (lane == 0) {
            const float sc = scales[row];
            const float bz = bias[row];
#pragma unroll
            for (int b = 0; b < 4; ++b)
                out[(size_t)b * OUT_F + row] = acc[b] * sc + bz;
        }

        row = nrow;
    }
}

}  // namespace

extern "C" void kernel_launch(void* const* d_in, const int* in_sizes, int n_in,
                              void* d_out, int out_size, void* d_ws, size_t ws_size,
                              hipStream_t stream) {
    const float* x      = (const float*)d_in[0];
    const int*   qw     = (const int*)d_in[1];
    const float* scales = (const float*)d_in[2];
    const float* bias   = (const float*)d_in[3];
    float*       out    = (float*)d_out;

    qlinear_kernel<<<NBLK, 256, 0, stream>>>(x, qw, scales, bias, out);
}

// Round 9
// 34.929 us; speedup vs baseline: 4.1743x; 4.1743x over previous
//
#include <hip/hip_runtime.h>

namespace {

constexpr int OUT_F = 11008;
constexpr int IN_F  = 4096;
constexpr int R4    = IN_F / 4;          // 1024 vec4 per row (x and qw)
constexpr int NLOAD = IN_F / (64 * 4);   // 16 int4 loads per lane per row
constexpr int NBLK  = 512;               // persistent: 2 blocks/CU
constexpr int NWAVE = NBLK * 4;          // 2048 waves
constexpr int NITER = (OUT_F + NWAVE - 1) / NWAVE;  // 6 (compile-time)

typedef int   int4v   __attribute__((ext_vector_type(4)));
typedef float float4v __attribute__((ext_vector_type(4)));

__global__ __launch_bounds__(256) void qlinear_kernel(
    const float* __restrict__ x,       // [4, IN_F]
    const int*   __restrict__ qw,      // [OUT_F, IN_F]
    const float* __restrict__ scales,  // [OUT_F]
    const float* __restrict__ bias,    // [OUT_F]
    float*       __restrict__ out)     // [4, OUT_F]
{
    __shared__ float4v xs[4 * R4];     // 64 KB fp32 (exact), staged ONCE

    const int tid  = threadIdx.x;
    const int lane = tid & 63;
    const int wave_gid = blockIdx.x * 4 + (tid >> 6);  // 0..2047

    const int4v* qw4 = (const int4v*)qw;

    // Single per-row weight buffer. CRITICAL (session rule, r6/r7/r8 evidence):
    // every write to buf[] is UNCONDITIONAL at runtime — conditional writes
    // under runtime branches demote the array to scratch (225 MB WRITE_SIZE).
    int4v buf[NLOAD];

    // Prefetch first row BEFORE staging x: HBM pipe busy during the stage.
    {
        const int4v* wp = qw4 + (size_t)wave_gid * R4;
#pragma unroll
        for (int i = 0; i < NLOAD; ++i)
            buf[i] = wp[i * 64 + lane];
    }

    const float4v* xg = (const float4v*)x;
#pragma unroll
    for (int j = 0; j < (4 * R4) / 256; ++j)     // 16 iters x 256 threads
        xs[j * 256 + tid] = xg[j * 256 + tid];
    __syncthreads();

    // Fully unrolled: straight-line code, all buf[] guards compile-time.
#pragma unroll
    for (int it = 0; it < NITER; ++it) {
        const int cur = wave_gid + it * NWAVE;

        float acc[4] = {0.f, 0.f, 0.f, 0.f};
#pragma unroll
        for (int k = 0; k < NLOAD; ++k) {
            float4v xv[4];
#pragma unroll
            for (int b = 0; b < 4; ++b)
                xv[b] = xs[b * R4 + k * 64 + lane];
            float4v wf;
            wf.x = (float)buf[k].x;
            wf.y = (float)buf[k].y;
            wf.z = (float)buf[k].z;
            wf.w = (float)buf[k].w;
#pragma unroll
            for (int b = 0; b < 4; ++b) {
                acc[b] += wf.x * xv[b].x;
                acc[b] += wf.y * xv[b].y;
                acc[b] += wf.z * xv[b].z;
                acc[b] += wf.w * xv[b].w;
            }
        }

        if (it + 1 < NITER) {  // compile-time guard (it is an unroll constant)
            // Runtime-clamped ADDRESS, unconditional loads: waves whose next
            // row is out of range stream row 0 (L3-hot, ~zero HBM cost) and
            // simply never store it.
            int nxt = wave_gid + (it + 1) * NWAVE;
            nxt = (nxt < OUT_F) ? nxt : 0;
            const int4v* wp = qw4 + (size_t)nxt * R4;
#pragma unroll
            for (int i = 0; i < NLOAD; ++i)
                buf[i] = wp[i * 64 + lane];   // flies during butterfly+store
        }

        // Butterfly reduction across the 64 lanes.
#pragma unroll
        for (int b = 0; b < 4; ++b) {
#pragma unroll
            for (int m = 32; m >= 1; m >>= 1)
                acc[b] += __shfl_xor(acc[b], m, 64);
        }

        if (cur < OUT_F && lane == 0) {   // scalar predicate, no array writes
            const float sc = scales[cur];
            const float bz = bias[cur];
#pragma unroll
            for (int b = 0; b < 4; ++b)
                out[(size_t)b * OUT_F + cur] = acc[b] * sc + bz;
        }
    }
}

}  // namespace

extern "C" void kernel_launch(void* const* d_in, const int* in_sizes, int n_in,
                              void* d_out, int out_size, void* d_ws, size_t ws_size,
                              hipStream_t stream) {
    const float* x      = (const float*)d_in[0];
    const int*   qw     = (const int*)d_in[1];
    const float* scales = (const float*)d_in[2];
    const float* bias   = (const float*)d_in[3];
    float*       out    = (float*)d_out;

    qlinear_kernel<<<NBLK, 256, 0, stream>>>(x, qw, scales, bias, out);
}